// Round 2
// baseline (499.229 us; speedup 1.0000x reference)
//
#include <hip/hip_runtime.h>

// Problem constants
#define B_   1024
#define E_   200
#define NE_  50000
#define OC_  32
#define FW_  9
#define WP_  192
#define FCIN 6144   // OC*WP
#define CATK 400    // E+R
#define KDIM 288    // OC*FW

typedef __attribute__((ext_vector_type(8))) short short8;
typedef __attribute__((ext_vector_type(4))) float floatx4;
typedef __attribute__((ext_vector_type(4))) unsigned short ushort4v;

static __device__ __forceinline__ float bf2f(unsigned short u) {
  return __uint_as_float(((unsigned)u) << 16);
}
static __device__ __forceinline__ unsigned short f2bf(float f) {
  unsigned u = __float_as_uint(f);
  u += 0x7FFFu + ((u >> 16) & 1u);   // RNE
  return (unsigned short)(u >> 16);
}

// ---------------- fp32 -> bf16 bulk convert (float4 in, ushort4 out) ----------------
__global__ __launch_bounds__(256) void k_cvt(
    const float* __restrict__ in, unsigned short* __restrict__ out, int n4) {
  int i = blockIdx.x * 256 + threadIdx.x;
  if (i >= n4) return;
  float4 v = ((const float4*)in)[i];
  ushort4v o = {f2bf(v.x), f2bf(v.y), f2bf(v.z), f2bf(v.w)};
  ((ushort4v*)out)[i] = o;
}

// ---------------- gather+convert: cat[1024][400] (es|ec), rbuf[1024][200] ----------------
__global__ __launch_bounds__(256) void k_gather(
    const int* __restrict__ e_s, const int* __restrict__ q_s, const int* __restrict__ e_c,
    const float* __restrict__ ent, const float* __restrict__ rel,
    unsigned short* __restrict__ cat, unsigned short* __restrict__ rbuf) {
  int idx = blockIdx.x * 256 + threadIdx.x;
  if (idx < B_ * CATK) {
    int s = idx / CATK, i = idx - s * CATK;
    int row = (i < E_) ? e_s[s] : e_c[s];
    int col = (i < E_) ? i : i - E_;
    cat[idx] = f2bf(ent[row * E_ + col]);
  } else {
    int j = idx - B_ * CATK;
    if (j < B_ * E_) {
      int s = j / E_, i = j - s * E_;
      rbuf[j] = f2bf(rel[q_s[s] * E_ + i]);
    }
  }
}

// ------------- transpose+pad+convert: out[n*K+k] = (n<N) ? bf16(in[k*N+n]) : 0 -------------
__global__ __launch_bounds__(256) void k_transpose(
    const float* __restrict__ in, unsigned short* __restrict__ out,
    int N, int Npad, int K) {
  int idx = blockIdx.x * 256 + threadIdx.x;
  if (idx >= Npad * K) return;
  int n = idx / K, k = idx - n * K;
  out[idx] = (n < N) ? f2bf(in[k * N + n]) : (unsigned short)0;
}

// ---------------- shared 64x16 GEMM tile (4 waves; wave w = rows m0+16w..+15) ----------------
// A: [M][lda] bf16 row-major. Bt: [n][ldb] bf16 (row n = col n of B). K = NK*32 + RQ*8.
template<int NK, int RQ>
static __device__ __forceinline__ floatx4 gemm_64x16(
    const unsigned short* __restrict__ A, int lda,
    const unsigned short* __restrict__ Bt, int ldb, int m0, int n0) {
  int lane = threadIdx.x & 63;
  int wv   = threadIdx.x >> 6;
  int l16  = lane & 15, quad = lane >> 4;
  const unsigned short* ap = A  + (long)(m0 + 16 * wv + l16) * lda + quad * 8;
  const unsigned short* bp = Bt + (long)(n0 + l16) * ldb + quad * 8;
  floatx4 acc = {0.f, 0.f, 0.f, 0.f};
#pragma unroll 4
  for (int ks = 0; ks < NK; ks++) {
    short8 a = *(const short8*)(ap + ks * 32);
    short8 b = *(const short8*)(bp + ks * 32);
    acc = __builtin_amdgcn_mfma_f32_16x16x32_bf16(a, b, acc, 0, 0, 0);
  }
  if (RQ > 0) {  // K remainder: quads < RQ hold real data, rest contribute zeros
    short8 z = {0,0,0,0,0,0,0,0};
    short8 a = (quad < RQ) ? *(const short8*)(ap + NK * 32) : z;
    short8 b = (quad < RQ) ? *(const short8*)(bp + NK * 32) : z;
    acc = __builtin_amdgcn_mfma_f32_16x16x32_bf16(a, b, acc, 0, 0, 0);
  }
  return acc;
}

// ---------------- e1 = cat @ W1 + W1_b ; bn0 -> xbuf[1024][200] bf16 ----------------
// K=400 = 12*32 + 2*8
__global__ __launch_bounds__(256) void k_gemm_e1(
    const unsigned short* __restrict__ cat, const unsigned short* __restrict__ W1T,
    const float* __restrict__ W1b,
    const float* __restrict__ g0, const float* __restrict__ b0,
    const float* __restrict__ m0p, const float* __restrict__ v0,
    unsigned short* __restrict__ xbuf) {
  int m0 = blockIdx.x * 64, n0 = blockIdx.y * 16;
  floatx4 acc = gemm_64x16<12, 2>(cat, CATK, W1T, CATK, m0, n0);
  int lane = threadIdx.x & 63, wv = threadIdx.x >> 6;
  int l16 = lane & 15, quad = lane >> 4;
  int j = n0 + l16;
  if (j < E_) {
    float s0  = g0[0] * rsqrtf(v0[0] + 1e-5f);
    float off = (W1b[j] - m0p[0]) * s0 + b0[0];
    int rbase = m0 + 16 * wv + quad * 4;
#pragma unroll
    for (int i = 0; i < 4; i++)
      xbuf[(rbase + i) * E_ + j] = f2bf(acc[i] * s0 + off);
  }
}

// ------- ktil = (r @ fc1_w + fc1_b) * s1[o] -> kbuf[1024][288] bf16 (bn1 scale folded) -------
// K=200 = 6*32 + 1*8
__global__ __launch_bounds__(256) void k_gemm_k(
    const unsigned short* __restrict__ rbuf, const unsigned short* __restrict__ fc1T,
    const float* __restrict__ fc1b,
    const float* __restrict__ g1, const float* __restrict__ v1,
    unsigned short* __restrict__ kbuf) {
  int m0 = blockIdx.x * 64, n0 = blockIdx.y * 16;
  floatx4 acc = gemm_64x16<6, 1>(rbuf, E_, fc1T, E_, m0, n0);
  int lane = threadIdx.x & 63, wv = threadIdx.x >> 6;
  int l16 = lane & 15, quad = lane >> 4;
  int c = n0 + l16;              // < 288 always (288 = 18*16)
  int o = c / FW_;
  float s1 = g1[o] * rsqrtf(v1[o] + 1e-5f);
  float fb = fc1b[c];
  int rbase = m0 + 16 * wv + quad * 4;
#pragma unroll
  for (int i = 0; i < 4; i++)
    kbuf[(rbase + i) * KDIM + c] = f2bf((acc[i] + fb) * s1);
}

// ---------------- per-sample conv + bn1 bias -> flat[1024][6144] bf16 ----------------
__global__ __launch_bounds__(256) void k_conv(
    const unsigned short* __restrict__ xbuf, const unsigned short* __restrict__ kbuf,
    const float* __restrict__ g1, const float* __restrict__ b1,
    const float* __restrict__ m1, const float* __restrict__ v1,
    unsigned short* __restrict__ flat) {
  __shared__ float xs[E_];
  __shared__ float ks[KDIM];
  __shared__ float beta[OC_];
  int b = blockIdx.x, tid = threadIdx.x;
  if (tid < E_)  xs[tid] = bf2f(xbuf[b * E_ + tid]);
  for (int i = tid; i < KDIM; i += 256) ks[i] = bf2f(kbuf[b * KDIM + i]);
  if (tid < OC_) {
    float s = g1[tid] * rsqrtf(v1[tid] + 1e-5f);
    beta[tid] = b1[tid] - m1[tid] * s;
  }
  __syncthreads();
#pragma unroll
  for (int u = 0; u < FCIN / 256; u++) {
    int t = u * 256 + tid;
    int o = t / WP_, p = t - o * WP_;
    float acc = beta[o];
#pragma unroll
    for (int w = 0; w < FW_; w++) acc += xs[p + w] * ks[o * FW_ + w];
    flat[b * FCIN + t] = f2bf(acc);
  }
}

// ---------------- h = relu(bn2(flat @ fc_w + fc_b)) -> hbuf[1024][200] bf16 ----------------
// K=6144 = 192*32
__global__ __launch_bounds__(256) void k_gemm_fc(
    const unsigned short* __restrict__ flat, const unsigned short* __restrict__ fcwT,
    const float* __restrict__ fcb,
    const float* __restrict__ g2, const float* __restrict__ b2,
    const float* __restrict__ m2, const float* __restrict__ v2,
    unsigned short* __restrict__ hbuf) {
  int m0 = blockIdx.x * 64, n0 = blockIdx.y * 16;
  floatx4 acc = gemm_64x16<192, 0>(flat, FCIN, fcwT, FCIN, m0, n0);
  int lane = threadIdx.x & 63, wv = threadIdx.x >> 6;
  int l16 = lane & 15, quad = lane >> 4;
  int j = n0 + l16;
  if (j < E_) {
    float s2 = g2[j] * rsqrtf(v2[j] + 1e-5f);
    float hb = (fcb[j] - m2[j]) * s2 + b2[j];
    int rbase = m0 + 16 * wv + quad * 4;
#pragma unroll
    for (int i = 0; i < 4; i++) {
      float h = fmaxf(acc[i] * s2 + hb, 0.f);
      hbuf[(rbase + i) * E_ + j] = f2bf(h);
    }
  }
}

// ---------------- out = sigmoid(h @ entity^T + bias) -> d_out[1024][50000] fp32 ----------------
// 64x64 tile per block; entb [NE][200] bf16 is the Bt layout. K=200 = 6*32 + 1*8.
__global__ __launch_bounds__(256) void k_gemm_out(
    const unsigned short* __restrict__ hbuf, const unsigned short* __restrict__ entb,
    const float* __restrict__ bias, float* __restrict__ out) {
  int m0 = blockIdx.x * 64;      // 16 m-tiles (fast dim -> consecutive blocks share B tile)
  int n0 = blockIdx.y * 64;      // 782 n-tiles
  int lane = threadIdx.x & 63, wv = threadIdx.x >> 6;
  int l16 = lane & 15, quad = lane >> 4;
  const unsigned short* ap = hbuf + (long)(m0 + 16 * wv + l16) * E_ + quad * 8;
  int ncol[4]; bool bok[4]; const unsigned short* bp[4];
#pragma unroll
  for (int f = 0; f < 4; f++) {
    ncol[f] = n0 + 16 * f + l16;
    bok[f]  = ncol[f] < NE_;
    bp[f]   = entb + (long)(bok[f] ? ncol[f] : 0) * E_ + quad * 8;  // clamped addr
  }
  floatx4 acc[4];
#pragma unroll
  for (int f = 0; f < 4; f++) acc[f] = (floatx4){0.f, 0.f, 0.f, 0.f};
  short8 z = {0,0,0,0,0,0,0,0};
#pragma unroll
  for (int ks = 0; ks < 6; ks++) {
    short8 a = *(const short8*)(ap + ks * 32);
#pragma unroll
    for (int f = 0; f < 4; f++) {
      short8 b = bok[f] ? *(const short8*)(bp[f] + ks * 32) : z;
      acc[f] = __builtin_amdgcn_mfma_f32_16x16x32_bf16(a, b, acc[f], 0, 0, 0);
    }
  }
  { // K remainder: k = 192..199, quad 0 only
    short8 a = (quad == 0) ? *(const short8*)(ap + 192) : z;
#pragma unroll
    for (int f = 0; f < 4; f++) {
      short8 b = (quad == 0 && bok[f]) ? *(const short8*)(bp[f] + 192) : z;
      acc[f] = __builtin_amdgcn_mfma_f32_16x16x32_bf16(a, b, acc[f], 0, 0, 0);
    }
  }
  int rbase = m0 + 16 * wv + quad * 4;
#pragma unroll
  for (int f = 0; f < 4; f++) {
    if (!bok[f]) continue;
    float bi = bias[ncol[f]];
#pragma unroll
    for (int i = 0; i < 4; i++) {
      float logit = acc[f][i] + bi;
      float sg = 1.f / (1.f + __expf(-logit));
      out[(long)(rbase + i) * NE_ + ncol[f]] = sg;
    }
  }
}

extern "C" void kernel_launch(void* const* d_in, const int* in_sizes, int n_in,
                              void* d_out, int out_size, void* d_ws, size_t ws_size,
                              hipStream_t stream) {
  const int* e_s = (const int*)d_in[0];
  const int* q_s = (const int*)d_in[1];
  const int* e_c = (const int*)d_in[2];
  const float* ent  = (const float*)d_in[3];
  const float* rel  = (const float*)d_in[4];
  const float* W1w  = (const float*)d_in[5];
  const float* W1b  = (const float*)d_in[6];
  const float* fc1w = (const float*)d_in[7];
  const float* fc1b = (const float*)d_in[8];
  const float* fcw  = (const float*)d_in[9];
  const float* fcb  = (const float*)d_in[10];
  const float* g0 = (const float*)d_in[11];
  const float* b0 = (const float*)d_in[12];
  const float* m0 = (const float*)d_in[13];
  const float* v0 = (const float*)d_in[14];
  const float* g1 = (const float*)d_in[15];
  const float* b1 = (const float*)d_in[16];
  const float* m1 = (const float*)d_in[17];
  const float* v1 = (const float*)d_in[18];
  const float* g2 = (const float*)d_in[19];
  const float* b2 = (const float*)d_in[20];
  const float* m2 = (const float*)d_in[21];
  const float* v2 = (const float*)d_in[22];
  const float* bias = (const float*)d_in[23];
  float* out = (float*)d_out;

  // Workspace layout (u16 bf16 buffers, 256 B pad between regions; total ~38.1 MB)
  char* w = (char*)d_ws;
  unsigned short* entb = (unsigned short*)(w + 0);          // 20,000,000 B [50000][200]
  unsigned short* cat  = (unsigned short*)(w + 20000256);   //    819,200 B [1024][400]
  unsigned short* rbuf = (unsigned short*)(w + 20819712);   //    409,600 B [1024][200]
  unsigned short* W1T  = (unsigned short*)(w + 21229568);   //    166,400 B [208][400]
  unsigned short* fc1T = (unsigned short*)(w + 21396224);   //    115,200 B [288][200]
  unsigned short* fcwT = (unsigned short*)(w + 21511680);   //  2,555,904 B [208][6144]
  unsigned short* xbuf = (unsigned short*)(w + 24067840);   //    409,600 B [1024][200]
  unsigned short* kbuf = (unsigned short*)(w + 24477696);   //    589,824 B [1024][288]
  unsigned short* flat = (unsigned short*)(w + 25067776);   // 12,582,912 B [1024][6144]
  unsigned short* hbuf = (unsigned short*)(w + 37650944);   //    409,600 B [1024][200]
  // end = 38,060,544 (+256 pad)

  k_cvt<<<dim3((NE_ * E_ / 4 + 255) / 256), dim3(256), 0, stream>>>(ent, entb, NE_ * E_ / 4);
  k_gather<<<dim3((B_ * CATK + B_ * E_) / 256), dim3(256), 0, stream>>>(
      e_s, q_s, e_c, ent, rel, cat, rbuf);
  k_transpose<<<dim3((208 * CATK + 255) / 256), dim3(256), 0, stream>>>(W1w, W1T, 200, 208, CATK);
  k_transpose<<<dim3((KDIM * E_ + 255) / 256), dim3(256), 0, stream>>>(fc1w, fc1T, KDIM, KDIM, E_);
  k_transpose<<<dim3((208 * FCIN + 255) / 256), dim3(256), 0, stream>>>(fcw, fcwT, 200, 208, FCIN);

  k_gemm_e1<<<dim3(16, 13), dim3(256), 0, stream>>>(cat, W1T, W1b, g0, b0, m0, v0, xbuf);
  k_gemm_k<<<dim3(16, 18), dim3(256), 0, stream>>>(rbuf, fc1T, fc1b, g1, v1, kbuf);
  k_conv<<<dim3(B_), dim3(256), 0, stream>>>(xbuf, kbuf, g1, b1, m1, v1, flat);
  k_gemm_fc<<<dim3(16, 13), dim3(256), 0, stream>>>(flat, fcwT, fcb, g2, b2, m2, v2, hbuf);
  k_gemm_out<<<dim3(16, 782), dim3(256), 0, stream>>>(hbuf, entb, bias, out);
}

// Round 3
// 446.386 us; speedup vs baseline: 1.1184x; 1.1184x over previous
//
#include <hip/hip_runtime.h>

// Problem constants
#define B_   1024
#define E_   200
#define NE_  50000
#define OC_  32
#define FW_  9
#define WP_  192
#define FCIN 6144   // OC*WP
#define CATK 400    // E+R
#define KDIM 288    // OC*FW

typedef __attribute__((ext_vector_type(8))) short short8;
typedef __attribute__((ext_vector_type(4))) float floatx4;
typedef __attribute__((ext_vector_type(4))) unsigned short ushort4v;

static __device__ __forceinline__ float bf2f(unsigned short u) {
  return __uint_as_float(((unsigned)u) << 16);
}
static __device__ __forceinline__ unsigned short f2bf(float f) {
  unsigned u = __float_as_uint(f);
  u += 0x7FFFu + ((u >> 16) & 1u);   // RNE
  return (unsigned short)(u >> 16);
}

// ---------------- fp32 -> bf16 bulk convert (float4 in, ushort4 out) ----------------
__global__ __launch_bounds__(256) void k_cvt(
    const float* __restrict__ in, unsigned short* __restrict__ out, int n4) {
  int i = blockIdx.x * 256 + threadIdx.x;
  if (i >= n4) return;
  float4 v = ((const float4*)in)[i];
  ushort4v o = {f2bf(v.x), f2bf(v.y), f2bf(v.z), f2bf(v.w)};
  ((ushort4v*)out)[i] = o;
}

// ---------------- gather+convert: cat[1024][400] (es|ec), rbuf[1024][200] ----------------
__global__ __launch_bounds__(256) void k_gather(
    const int* __restrict__ e_s, const int* __restrict__ q_s, const int* __restrict__ e_c,
    const float* __restrict__ ent, const float* __restrict__ rel,
    unsigned short* __restrict__ cat, unsigned short* __restrict__ rbuf) {
  int idx = blockIdx.x * 256 + threadIdx.x;
  if (idx < B_ * CATK) {
    int s = idx / CATK, i = idx - s * CATK;
    int row = (i < E_) ? e_s[s] : e_c[s];
    int col = (i < E_) ? i : i - E_;
    cat[idx] = f2bf(ent[row * E_ + col]);
  } else {
    int j = idx - B_ * CATK;
    if (j < B_ * E_) {
      int s = j / E_, i = j - s * E_;
      rbuf[j] = f2bf(rel[q_s[s] * E_ + i]);
    }
  }
}

// ------- LDS tile transpose+pad+convert: in[k*N+n] fp32 -> out[n*K+k] bf16 (n<Npad) -------
// Coalesced on both sides. Grid: (ceil(Npad/64), ceil(K/64)).
__global__ __launch_bounds__(256) void k_transpose_lds(
    const float* __restrict__ in, unsigned short* __restrict__ out,
    int N, int Npad, int K) {
  __shared__ unsigned short lds[64][65];
  int n0 = blockIdx.x * 64, k0 = blockIdx.y * 64;
  int tx = threadIdx.x & 63, ty = threadIdx.x >> 6;   // ty in 0..3
#pragma unroll
  for (int kk = 0; kk < 16; kk++) {
    int k = k0 + ty + 4 * kk;
    int n = n0 + tx;
    unsigned short v = 0;
    if (k < K && n < N) v = f2bf(in[(long)k * N + n]);
    lds[ty + 4 * kk][tx] = v;
  }
  __syncthreads();
#pragma unroll
  for (int kk = 0; kk < 16; kk++) {
    int k = k0 + tx;
    int n = n0 + ty + 4 * kk;
    if (n < Npad && k < K) out[(long)n * K + k] = lds[tx][ty + 4 * kk];
  }
}

// ---------------- shared 64x16 GEMM tile (4 waves; wave w = rows m0+16w..+15) ----------------
// A: [M][lda] bf16 row-major. Bt: [n][ldb] bf16 (row n = col n of B). K = NK*32 + RQ*8.
template<int NK, int RQ>
static __device__ __forceinline__ floatx4 gemm_64x16(
    const unsigned short* __restrict__ A, int lda,
    const unsigned short* __restrict__ Bt, int ldb, int m0, int n0) {
  int lane = threadIdx.x & 63;
  int wv   = threadIdx.x >> 6;
  int l16  = lane & 15, quad = lane >> 4;
  const unsigned short* ap = A  + (long)(m0 + 16 * wv + l16) * lda + quad * 8;
  const unsigned short* bp = Bt + (long)(n0 + l16) * ldb + quad * 8;
  floatx4 acc = {0.f, 0.f, 0.f, 0.f};
#pragma unroll 4
  for (int ks = 0; ks < NK; ks++) {
    short8 a = *(const short8*)(ap + ks * 32);
    short8 b = *(const short8*)(bp + ks * 32);
    acc = __builtin_amdgcn_mfma_f32_16x16x32_bf16(a, b, acc, 0, 0, 0);
  }
  if (RQ > 0) {  // K remainder: quads < RQ hold real data, rest contribute zeros
    short8 z = {0,0,0,0,0,0,0,0};
    short8 a = (quad < RQ) ? *(const short8*)(ap + NK * 32) : z;
    short8 b = (quad < RQ) ? *(const short8*)(bp + NK * 32) : z;
    acc = __builtin_amdgcn_mfma_f32_16x16x32_bf16(a, b, acc, 0, 0, 0);
  }
  return acc;
}

// ---------------- e1 = cat @ W1 + W1_b ; bn0 -> xbuf[1024][200] bf16 ----------------
// K=400 = 12*32 + 2*8
__global__ __launch_bounds__(256) void k_gemm_e1(
    const unsigned short* __restrict__ cat, const unsigned short* __restrict__ W1T,
    const float* __restrict__ W1b,
    const float* __restrict__ g0, const float* __restrict__ b0,
    const float* __restrict__ m0p, const float* __restrict__ v0,
    unsigned short* __restrict__ xbuf) {
  int m0 = blockIdx.x * 64, n0 = blockIdx.y * 16;
  floatx4 acc = gemm_64x16<12, 2>(cat, CATK, W1T, CATK, m0, n0);
  int lane = threadIdx.x & 63, wv = threadIdx.x >> 6;
  int l16 = lane & 15, quad = lane >> 4;
  int j = n0 + l16;
  if (j < E_) {
    float s0  = g0[0] * rsqrtf(v0[0] + 1e-5f);
    float off = (W1b[j] - m0p[0]) * s0 + b0[0];
    int rbase = m0 + 16 * wv + quad * 4;
#pragma unroll
    for (int i = 0; i < 4; i++)
      xbuf[(rbase + i) * E_ + j] = f2bf(acc[i] * s0 + off);
  }
}

// ------- ktil = (r @ fc1_w + fc1_b) * s1[o] -> kbuf[1024][288] bf16 (bn1 scale folded) -------
// K=200 = 6*32 + 1*8
__global__ __launch_bounds__(256) void k_gemm_k(
    const unsigned short* __restrict__ rbuf, const unsigned short* __restrict__ fc1T,
    const float* __restrict__ fc1b,
    const float* __restrict__ g1, const float* __restrict__ v1,
    unsigned short* __restrict__ kbuf) {
  int m0 = blockIdx.x * 64, n0 = blockIdx.y * 16;
  floatx4 acc = gemm_64x16<6, 1>(rbuf, E_, fc1T, E_, m0, n0);
  int lane = threadIdx.x & 63, wv = threadIdx.x >> 6;
  int l16 = lane & 15, quad = lane >> 4;
  int c = n0 + l16;              // < 288 always (288 = 18*16)
  int o = c / FW_;
  float s1 = g1[o] * rsqrtf(v1[o] + 1e-5f);
  float fb = fc1b[c];
  int rbase = m0 + 16 * wv + quad * 4;
#pragma unroll
  for (int i = 0; i < 4; i++)
    kbuf[(rbase + i) * KDIM + c] = f2bf((acc[i] + fb) * s1);
}

// ---------------- per-sample conv + bn1 bias -> flat[1024][6144] bf16 ----------------
__global__ __launch_bounds__(256) void k_conv(
    const unsigned short* __restrict__ xbuf, const unsigned short* __restrict__ kbuf,
    const float* __restrict__ g1, const float* __restrict__ b1,
    const float* __restrict__ m1, const float* __restrict__ v1,
    unsigned short* __restrict__ flat) {
  __shared__ float xs[E_];
  __shared__ float ks[KDIM];
  __shared__ float beta[OC_];
  int b = blockIdx.x, tid = threadIdx.x;
  if (tid < E_)  xs[tid] = bf2f(xbuf[b * E_ + tid]);
  for (int i = tid; i < KDIM; i += 256) ks[i] = bf2f(kbuf[b * KDIM + i]);
  if (tid < OC_) {
    float s = g1[tid] * rsqrtf(v1[tid] + 1e-5f);
    beta[tid] = b1[tid] - m1[tid] * s;
  }
  __syncthreads();
#pragma unroll
  for (int u = 0; u < FCIN / 256; u++) {
    int t = u * 256 + tid;
    int o = t / WP_, p = t - o * WP_;
    float acc = beta[o];
#pragma unroll
    for (int w = 0; w < FW_; w++) acc += xs[p + w] * ks[o * FW_ + w];
    flat[b * FCIN + t] = f2bf(acc);
  }
}

// ------------- flat @ fc_w, split-K x8 -> partial[8][1024][208] fp32 -------------
// K-chunk = 768 = 24*32. Grid (16, 13, 8).
__global__ __launch_bounds__(256) void k_gemm_fc(
    const unsigned short* __restrict__ flat, const unsigned short* __restrict__ fcwT,
    float* __restrict__ partial) {
  int m0 = blockIdx.x * 64, n0 = blockIdx.y * 16, kc = blockIdx.z;
  int lane = threadIdx.x & 63, wv = threadIdx.x >> 6;
  int l16 = lane & 15, quad = lane >> 4;
  const unsigned short* ap = flat + (long)(m0 + 16 * wv + l16) * FCIN + kc * 768 + quad * 8;
  const unsigned short* bp = fcwT + (long)(n0 + l16) * FCIN + kc * 768 + quad * 8;
  floatx4 acc = {0.f, 0.f, 0.f, 0.f};
#pragma unroll 4
  for (int ks = 0; ks < 24; ks++) {
    short8 a = *(const short8*)(ap + ks * 32);
    short8 b = *(const short8*)(bp + ks * 32);
    acc = __builtin_amdgcn_mfma_f32_16x16x32_bf16(a, b, acc, 0, 0, 0);
  }
  int j = n0 + l16;   // < 208 always
  int rbase = m0 + 16 * wv + quad * 4;
#pragma unroll
  for (int i = 0; i < 4; i++)
    partial[((long)kc * B_ + rbase + i) * 208 + j] = acc[i];
}

// ------------- reduce partials + bias + bn2 + relu -> hbuf[1024][200] bf16 -------------
__global__ __launch_bounds__(256) void k_fc_epi(
    const float* __restrict__ partial, const float* __restrict__ fcb,
    const float* __restrict__ g2, const float* __restrict__ b2,
    const float* __restrict__ m2, const float* __restrict__ v2,
    unsigned short* __restrict__ hbuf) {
  int idx = blockIdx.x * 256 + threadIdx.x;
  if (idx >= B_ * E_) return;
  int m = idx / E_, j = idx - m * E_;
  float s = 0.f;
#pragma unroll
  for (int kc = 0; kc < 8; kc++) s += partial[((long)kc * B_ + m) * 208 + j];
  float s2 = g2[j] * rsqrtf(v2[j] + 1e-5f);
  float h = (s + fcb[j] - m2[j]) * s2 + b2[j];
  hbuf[idx] = f2bf(fmaxf(h, 0.f));
}

// ---------------- out = sigmoid(h @ entity^T + bias) -> d_out[1024][50000] fp32 ----------------
// 128m x 64n tile per block, 4 waves (wave = 32 rows). Column-interleaved n-tiles:
// MFMA n-tile f covers cols {n0 + 4*j + f}, so each lane owns 4 consecutive output
// floats -> dwordx4 stores. XCD swizzle: g' = (g%8)*782 + g/8 gives each XCD a
// contiguous ~98 n-tile range (entb slice ~2.5 MB, fits 4 MB XCD L2).
__global__ __launch_bounds__(256) void k_gemm_out(
    const unsigned short* __restrict__ hbuf, const unsigned short* __restrict__ entb,
    const float* __restrict__ bias, float* __restrict__ out) {
  int g  = blockIdx.y * 8 + blockIdx.x;        // grid (8, 782)
  int gp = (g & 7) * 782 + (g >> 3);
  int m0 = (gp & 7) * 128;
  int n0 = (gp >> 3) * 64;
  int lane = threadIdx.x & 63, wv = threadIdx.x >> 6;
  int l16 = lane & 15, quad = lane >> 4;

  const unsigned short* ap0 = hbuf + (long)(m0 + 32 * wv + l16) * E_ + quad * 8;
  const unsigned short* ap1 = ap0 + 16 * E_;
  int nb = n0 + 4 * l16;                       // lane's base output col
  bool ok = nb < NE_;                          // NE%4==0 -> whole float4 valid or not
  const unsigned short* bp[4];
#pragma unroll
  for (int f = 0; f < 4; f++) {
    int n = nb + f;
    bp[f] = entb + (long)((n < NE_) ? n : 0) * E_ + quad * 8;
  }

  floatx4 acc[8];
#pragma unroll
  for (int i = 0; i < 8; i++) acc[i] = (floatx4){0.f, 0.f, 0.f, 0.f};

#pragma unroll 2
  for (int ks = 0; ks < 6; ks++) {
    short8 a0 = *(const short8*)(ap0 + ks * 32);
    short8 a1 = *(const short8*)(ap1 + ks * 32);
#pragma unroll
    for (int f = 0; f < 4; f++) {
      short8 b = *(const short8*)(bp[f] + ks * 32);
      acc[f]     = __builtin_amdgcn_mfma_f32_16x16x32_bf16(a0, b, acc[f], 0, 0, 0);
      acc[4 + f] = __builtin_amdgcn_mfma_f32_16x16x32_bf16(a1, b, acc[4 + f], 0, 0, 0);
    }
  }
  { // K remainder k=192..199 (quad 0 only)
    short8 z = {0,0,0,0,0,0,0,0};
    short8 a0 = (quad == 0) ? *(const short8*)(ap0 + 192) : z;
    short8 a1 = (quad == 0) ? *(const short8*)(ap1 + 192) : z;
#pragma unroll
    for (int f = 0; f < 4; f++) {
      short8 b = (quad == 0) ? *(const short8*)(bp[f] + 192) : z;
      acc[f]     = __builtin_amdgcn_mfma_f32_16x16x32_bf16(a0, b, acc[f], 0, 0, 0);
      acc[4 + f] = __builtin_amdgcn_mfma_f32_16x16x32_bf16(a1, b, acc[4 + f], 0, 0, 0);
    }
  }

  if (!ok) return;
  float4 bi = *(const float4*)(bias + nb);
#pragma unroll
  for (int t = 0; t < 2; t++) {
#pragma unroll
    for (int i = 0; i < 4; i++) {
      int row = m0 + 32 * wv + 16 * t + quad * 4 + i;
      float4 v;
      v.x = 1.f / (1.f + __expf(-(acc[t * 4 + 0][i] + bi.x)));
      v.y = 1.f / (1.f + __expf(-(acc[t * 4 + 1][i] + bi.y)));
      v.z = 1.f / (1.f + __expf(-(acc[t * 4 + 2][i] + bi.z)));
      v.w = 1.f / (1.f + __expf(-(acc[t * 4 + 3][i] + bi.w)));
      *(float4*)(out + (long)row * NE_ + nb) = v;
    }
  }
}

extern "C" void kernel_launch(void* const* d_in, const int* in_sizes, int n_in,
                              void* d_out, int out_size, void* d_ws, size_t ws_size,
                              hipStream_t stream) {
  const int* e_s = (const int*)d_in[0];
  const int* q_s = (const int*)d_in[1];
  const int* e_c = (const int*)d_in[2];
  const float* ent  = (const float*)d_in[3];
  const float* rel  = (const float*)d_in[4];
  const float* W1w  = (const float*)d_in[5];
  const float* W1b  = (const float*)d_in[6];
  const float* fc1w = (const float*)d_in[7];
  const float* fc1b = (const float*)d_in[8];
  const float* fcw  = (const float*)d_in[9];
  const float* fcb  = (const float*)d_in[10];
  const float* g0 = (const float*)d_in[11];
  const float* b0 = (const float*)d_in[12];
  const float* m0 = (const float*)d_in[13];
  const float* v0 = (const float*)d_in[14];
  const float* g1 = (const float*)d_in[15];
  const float* b1 = (const float*)d_in[16];
  const float* m1 = (const float*)d_in[17];
  const float* v1 = (const float*)d_in[18];
  const float* g2 = (const float*)d_in[19];
  const float* b2 = (const float*)d_in[20];
  const float* m2 = (const float*)d_in[21];
  const float* v2 = (const float*)d_in[22];
  const float* bias = (const float*)d_in[23];
  float* out = (float*)d_out;

  // Workspace layout (256 B padded regions; total ~44.9 MB)
  char* w = (char*)d_ws;
  unsigned short* entb = (unsigned short*)(w + 0);          // 20,000,000 B [50000][200]
  unsigned short* cat  = (unsigned short*)(w + 20000256);   //    819,200 B [1024][400]
  unsigned short* rbuf = (unsigned short*)(w + 20819712);   //    409,600 B [1024][200]
  unsigned short* W1T  = (unsigned short*)(w + 21229568);   //    166,400 B [208][400]
  unsigned short* fc1T = (unsigned short*)(w + 21396224);   //    115,200 B [288][200]
  unsigned short* fcwT = (unsigned short*)(w + 21511680);   //  2,555,904 B [208][6144]
  unsigned short* xbuf = (unsigned short*)(w + 24067840);   //    409,600 B [1024][200]
  unsigned short* kbuf = (unsigned short*)(w + 24477696);   //    589,824 B [1024][288]
  unsigned short* flat = (unsigned short*)(w + 25067776);   // 12,582,912 B [1024][6144]
  unsigned short* hbuf = (unsigned short*)(w + 37650944);   //    409,600 B [1024][200]
  float* partial       = (float*)(w + 38060800);            //  6,815,744 B [8][1024][208]
  // end = 44,876,544

  k_cvt<<<dim3((NE_ * E_ / 4 + 255) / 256), dim3(256), 0, stream>>>(ent, entb, NE_ * E_ / 4);
  k_gather<<<dim3((B_ * CATK + B_ * E_) / 256), dim3(256), 0, stream>>>(
      e_s, q_s, e_c, ent, rel, cat, rbuf);
  k_transpose_lds<<<dim3(4, 7),  dim3(256), 0, stream>>>(W1w,  W1T,  200, 208, CATK);
  k_transpose_lds<<<dim3(5, 4),  dim3(256), 0, stream>>>(fc1w, fc1T, 288, 288, E_);
  k_transpose_lds<<<dim3(4, 96), dim3(256), 0, stream>>>(fcw,  fcwT, 200, 208, FCIN);

  k_gemm_e1<<<dim3(16, 13), dim3(256), 0, stream>>>(cat, W1T, W1b, g0, b0, m0, v0, xbuf);
  k_gemm_k<<<dim3(16, 18), dim3(256), 0, stream>>>(rbuf, fc1T, fc1b, g1, v1, kbuf);
  k_conv<<<dim3(B_), dim3(256), 0, stream>>>(xbuf, kbuf, g1, b1, m1, v1, flat);
  k_gemm_fc<<<dim3(16, 13, 8), dim3(256), 0, stream>>>(flat, fcwT, partial);
  k_fc_epi<<<dim3((B_ * E_ + 255) / 256), dim3(256), 0, stream>>>(
      partial, fcb, g2, b2, m2, v2, hbuf);
  k_gemm_out<<<dim3(8, 782), dim3(256), 0, stream>>>(hbuf, entb, bias, out);
}